// Round 13
// baseline (33.910 us; speedup 1.0000x reference)
//
#include <hip/hip_runtime.h>

// B=16, N=128, F_IN=8, FC=256, H=256, E=N*(N-1)=16256, rows=B*E=260096, TAU=0.5
//
// Collapse (exact): graph is broadcast from graph[0,0] -> identical rows ->
// batchnorm over identical rows outputs exactly beta for both MLPs. Head input
// is one 512-vector [m2_beta, m2_beta] for ALL B*E rows: logits L[8] and
// prob=softmax(L) are computed ONCE; per-row work is only
// g_graph = softmax((L + gumbel)/TAU).
//
// Round-13: K3 polish — 2 ADJACENT rows/thread (contiguous 64B/thread,
// 4KB/wave per stream) + nontemporal loads for the read-once gumbel stream.
// 3 nodes: gate+f1p(64) -> f1r+f2+f3p(64) -> gumbel+p3reduce(508).
// R7/R8 measured: in-kernel cross-block sync is catastrophic on gfx950.

#define FC   256
#define HID  256
#define NOUT 8

typedef float f4 __attribute__((ext_vector_type(4)));

// ws float offsets
#define WS_P3 512                 // [64][8]  f3 partials
#define WS_P1 1024                // [64][256] f1 partials

// ---- K1: gate cols + f1 partials ---------------------------------------------
__global__ __launch_bounds__(256) void gate_f1p(
    const float* __restrict__ beta,
    const float* __restrict__ Wi, const float* __restrict__ Wn,
    const float* __restrict__ bi, const float* __restrict__ bn_b,
    const float* __restrict__ f1W,
    float* __restrict__ ws)
{
    const int b  = blockIdx.x;     // 0..63
    const int t  = threadIdx.x;    // 0..255 (= k mod 256)
    const int c0 = b * 4;

    const float ck = beta[t];
    const float4 wi0 = *reinterpret_cast<const float4*>(&Wi[(size_t)t * HID + c0]);
    const float4 wi1 = *reinterpret_cast<const float4*>(&Wi[(size_t)(t + 256) * HID + c0]);
    const float4 wn0 = *reinterpret_cast<const float4*>(&Wn[(size_t)t * HID + c0]);
    const float4 wn1 = *reinterpret_cast<const float4*>(&Wn[(size_t)(t + 256) * HID + c0]);

    float v[8];
    v[0] = ck * (wi0.x + wi1.x); v[1] = ck * (wi0.y + wi1.y);
    v[2] = ck * (wi0.z + wi1.z); v[3] = ck * (wi0.w + wi1.w);
    v[4] = ck * (wn0.x + wn1.x); v[5] = ck * (wn0.y + wn1.y);
    v[6] = ck * (wn0.z + wn1.z); v[7] = ck * (wn0.w + wn1.w);

    #pragma unroll
    for (int off = 32; off > 0; off >>= 1) {
        #pragma unroll
        for (int j = 0; j < 8; ++j) v[j] += __shfl_xor(v[j], off, 64);
    }

    __shared__ float lds[4][8];
    __shared__ float hv4[4];
    const int lane = t & 63, wid = t >> 6;
    if (lane == 0) {
        #pragma unroll
        for (int j = 0; j < 8; ++j) lds[wid][j] = v[j];
    }
    __syncthreads();
    if (t < 4) {
        const float ai = lds[0][t] + lds[1][t] + lds[2][t] + lds[3][t];
        const float an = lds[0][4 + t] + lds[1][4 + t] + lds[2][4 + t] + lds[3][4 + t];
        const int c = c0 + t;
        const float iv = 1.f / (1.f + __expf(-(ai + bi[c])));
        const float nv = tanhf(an + bn_b[c]);
        hv4[t] = (1.f - iv) * nv;          // h[c] = (1-i)*n
    }
    __syncthreads();

    // f1 partials: p1[b][t] = sum_{i<4} h[c0+i] * f1W[c0+i][t]
    const float p = hv4[0] * f1W[(size_t)(c0 + 0) * HID + t]
                  + hv4[1] * f1W[(size_t)(c0 + 1) * HID + t]
                  + hv4[2] * f1W[(size_t)(c0 + 2) * HID + t]
                  + hv4[3] * f1W[(size_t)(c0 + 3) * HID + t];
    ws[WS_P1 + b * 256 + t] = p;
}

// ---- K2: reduce p1 -> o1; f2 cols -> o2[c0..c0+4); f3 partials ---------------
__global__ __launch_bounds__(256) void f1r_f2_f3p(
    const float* __restrict__ f1b,
    const float* __restrict__ f2W, const float* __restrict__ f2b,
    const float* __restrict__ f3W,
    float* __restrict__ ws)
{
    const int b  = blockIdx.x;     // 0..63
    const int t  = threadIdx.x;    // 0..255
    const int c0 = b * 4;

    // o1[t] = relu(sum_b p1[b][t] + f1b[t])
    float a = 0.f;
    #pragma unroll 8
    for (int k = 0; k < 64; ++k) a += ws[WS_P1 + k * 256 + t];
    const float o1 = fmaxf(a + f1b[t], 0.f);

    // f2 columns c0..c0+3
    const float4 w = *reinterpret_cast<const float4*>(&f2W[(size_t)t * HID + c0]);
    float v[4] = {o1 * w.x, o1 * w.y, o1 * w.z, o1 * w.w};
    #pragma unroll
    for (int off = 32; off > 0; off >>= 1) {
        #pragma unroll
        for (int j = 0; j < 4; ++j) v[j] += __shfl_xor(v[j], off, 64);
    }

    __shared__ float lds[4][4];
    __shared__ float o2s[4];
    const int lane = t & 63, wid = t >> 6;
    if (lane == 0) {
        #pragma unroll
        for (int j = 0; j < 4; ++j) lds[wid][j] = v[j];
    }
    __syncthreads();
    if (t < 4) {
        const float s = lds[0][t] + lds[1][t] + lds[2][t] + lds[3][t];
        o2s[t] = fmaxf(s + f2b[c0 + t], 0.f);
    }
    __syncthreads();

    // f3 partials: p3[b][j] = sum_{i<4} o2[c0+i] * f3W[c0+i][j]
    if (t < NOUT) {
        const float p = o2s[0] * f3W[(size_t)(c0 + 0) * NOUT + t]
                      + o2s[1] * f3W[(size_t)(c0 + 1) * NOUT + t]
                      + o2s[2] * f3W[(size_t)(c0 + 2) * NOUT + t]
                      + o2s[3] * f3W[(size_t)(c0 + 3) * NOUT + t];
        ws[WS_P3 + b * NOUT + t] = p;
    }
}

// ---- K3: reduce p3 -> L, softmax; gumbel on 2 ADJACENT rows/thread ------------
__global__ __launch_bounds__(256) void gumbel_red(
    const float* __restrict__ gn,   // [rows, 8] fp32
    const float* __restrict__ ws,   // p3 at WS_P3
    const float* __restrict__ f3b,  // [8]
    float* __restrict__ out,        // g_graph [rows,8] then prob [rows,8]
    int rows)
{
    const int t  = threadIdx.x;
    const long r0 = ((long)blockIdx.x * 256 + t) * 2;   // rows r0, r0+1

    // issue both rows' gumbel loads first (64B contiguous/thread, NT read-once)
    f4 g0 = {0.f,0.f,0.f,0.f}, g1 = g0, g2 = g0, g3 = g0;
    const bool okA = r0 < rows, okB = (r0 + 1) < rows;
    if (okA) {
        const f4* gp = reinterpret_cast<const f4*>(gn + (size_t)r0 * NOUT);
        g0 = __builtin_nontemporal_load(gp);
        g1 = __builtin_nontemporal_load(gp + 1);
        if (okB) {
            g2 = __builtin_nontemporal_load(gp + 2);
            g3 = __builtin_nontemporal_load(gp + 3);
        }
    }

    // preamble: reduce p3 -> L, softmax (wave 0 only; hidden under loads)
    __shared__ float sLp[16];
    if (t < 64) {
        const float4 pa = *reinterpret_cast<const float4*>(&ws[WS_P3 + t * NOUT]);
        const float4 pb = *reinterpret_cast<const float4*>(&ws[WS_P3 + t * NOUT + 4]);
        float v[NOUT] = {pa.x, pa.y, pa.z, pa.w, pb.x, pb.y, pb.z, pb.w};
        #pragma unroll
        for (int off = 32; off > 0; off >>= 1) {
            #pragma unroll
            for (int j = 0; j < NOUT; ++j) v[j] += __shfl_xor(v[j], off, 64);
        }
        if (t == 0) {
            float L[NOUT];
            #pragma unroll
            for (int j = 0; j < NOUT; ++j) L[j] = v[j] + f3b[j];
            float m = L[0];
            #pragma unroll
            for (int j = 1; j < NOUT; ++j) m = fmaxf(m, L[j]);
            float e[NOUT], s = 0.f;
            #pragma unroll
            for (int j = 0; j < NOUT; ++j) { e[j] = __expf(L[j] - m); s += e[j]; }
            const float inv = 1.f / s;
            #pragma unroll
            for (int j = 0; j < NOUT; ++j) {
                sLp[j]     = 2.f * L[j];     // pre-scaled by 1/TAU = 2
                sLp[8 + j] = e[j] * inv;     // prob
            }
        }
    }
    __syncthreads();

    float L2[NOUT];
    #pragma unroll
    for (int j = 0; j < NOUT; ++j) L2[j] = sLp[j];
    const f4 pr0 = {sLp[8],  sLp[9],  sLp[10], sLp[11]};
    const f4 pr1 = {sLp[12], sLp[13], sLp[14], sLp[15]};

    // ---- row A (r0) ----
    if (okA) {
        float z[NOUT] = {g0.x, g0.y, g0.z, g0.w, g1.x, g1.y, g1.z, g1.w};
        float m = -1e30f;
        #pragma unroll
        for (int j = 0; j < NOUT; ++j) { z[j] = L2[j] + 2.f * z[j]; m = fmaxf(m, z[j]); }
        float s = 0.f;
        #pragma unroll
        for (int j = 0; j < NOUT; ++j) { z[j] = __expf(z[j] - m); s += z[j]; }
        const float inv = 1.f / s;
        f4* op = reinterpret_cast<f4*>(out + (size_t)r0 * NOUT);
        f4 z0 = {z[0]*inv, z[1]*inv, z[2]*inv, z[3]*inv};
        f4 z1 = {z[4]*inv, z[5]*inv, z[6]*inv, z[7]*inv};
        __builtin_nontemporal_store(z0, op);
        __builtin_nontemporal_store(z1, op + 1);
        f4* pp = reinterpret_cast<f4*>(out + (size_t)(rows + r0) * NOUT);
        __builtin_nontemporal_store(pr0, pp);
        __builtin_nontemporal_store(pr1, pp + 1);
    }
    // ---- row B (r0+1) ----
    if (okB) {
        float z[NOUT] = {g2.x, g2.y, g2.z, g2.w, g3.x, g3.y, g3.z, g3.w};
        float m = -1e30f;
        #pragma unroll
        for (int j = 0; j < NOUT; ++j) { z[j] = L2[j] + 2.f * z[j]; m = fmaxf(m, z[j]); }
        float s = 0.f;
        #pragma unroll
        for (int j = 0; j < NOUT; ++j) { z[j] = __expf(z[j] - m); s += z[j]; }
        const float inv = 1.f / s;
        f4* op = reinterpret_cast<f4*>(out + (size_t)(r0 + 1) * NOUT);
        f4 z0 = {z[0]*inv, z[1]*inv, z[2]*inv, z[3]*inv};
        f4 z1 = {z[4]*inv, z[5]*inv, z[6]*inv, z[7]*inv};
        __builtin_nontemporal_store(z0, op);
        __builtin_nontemporal_store(z1, op + 1);
        f4* pp = reinterpret_cast<f4*>(out + (size_t)(rows + r0 + 1) * NOUT);
        __builtin_nontemporal_store(pr0, pp);
        __builtin_nontemporal_store(pr1, pp + 1);
    }
}

extern "C" void kernel_launch(void* const* d_in, const int* in_sizes, int n_in,
                              void* d_out, int out_size, void* d_ws, size_t ws_size,
                              hipStream_t stream) {
    // 0 graph, 1 rel_rec, 2 rel_send, 3 gumbel_noise,
    // 4 m1_W1, 5 m1_b1, 6 m1_W2, 7 m1_b2, 8 m1_g, 9 m1_beta,
    // 10 m2_W1, 11 m2_b1, 12 m2_W2, 13 m2_b2, 14 m2_g, 15 m2_beta,
    // 16 Wi, 17 bi, 18 Wn, 19 bn_b, 20 f1_W, 21 f1_b, 22 f2_W, 23 f2_b,
    // 24 f3_W, 25 f3_b
    const float* gumbel  = (const float*)d_in[3];
    const float* m2_beta = (const float*)d_in[15];
    const float* Wi      = (const float*)d_in[16];
    const float* bi      = (const float*)d_in[17];
    const float* Wn      = (const float*)d_in[18];
    const float* bn_b    = (const float*)d_in[19];
    const float* f1W     = (const float*)d_in[20];
    const float* f1b     = (const float*)d_in[21];
    const float* f2W     = (const float*)d_in[22];
    const float* f2b     = (const float*)d_in[23];
    const float* f3W     = (const float*)d_in[24];
    const float* f3b     = (const float*)d_in[25];

    const int rows = in_sizes[3] / NOUT;   // 260096
    float* ws = (float*)d_ws;

    gate_f1p<<<64, 256, 0, stream>>>(m2_beta, Wi, Wn, bi, bn_b, f1W, ws);
    f1r_f2_f3p<<<64, 256, 0, stream>>>(f1b, f2W, f2b, f3W, ws);

    const int blocks = (rows + 511) / 512;   // 508
    gumbel_red<<<blocks, 256, 0, stream>>>(gumbel, ws, f3b, (float*)d_out, rows);
}

// Round 14
// 21.156 us; speedup vs baseline: 1.6028x; 1.6028x over previous
//
#include <hip/hip_runtime.h>

// B=16, N=128, F_IN=8, FC=256, H=256, E=N*(N-1)=16256, rows=B*E=260096, TAU=0.5
//
// Collapse (exact): graph is broadcast from graph[0,0] -> identical rows ->
// batchnorm over identical rows outputs exactly beta for both MLPs. Head input
// is one 512-vector [m2_beta, m2_beta] for ALL B*E rows: logits L[8] and
// prob=softmax(L) are computed ONCE; per-row work is only
// g_graph = softmax((L + gumbel)/TAU).
//
// Round-14: A/B isolating R13's regression. R13 bundled {adjacent-rows layout,
// NT loads}; adjacent rows break PER-INSTRUCTION coalescing (lane i's load at
// byte i*64 -> stride-64B gather, 4KB touched/1KB used per instruction).
// Revert to R12's strided 2-rows/thread (r, r+256: every load instruction is
// a contiguous 64x16B=1KB span); KEEP NT loads+stores to isolate the factor.
// R7/R8 measured: in-kernel cross-block sync is catastrophic on gfx950.

#define FC   256
#define HID  256
#define NOUT 8

typedef float f4 __attribute__((ext_vector_type(4)));

// ws float offsets
#define WS_P3 512                 // [64][8]  f3 partials
#define WS_P1 1024                // [64][256] f1 partials

// ---- K1: gate cols + f1 partials ---------------------------------------------
__global__ __launch_bounds__(256) void gate_f1p(
    const float* __restrict__ beta,
    const float* __restrict__ Wi, const float* __restrict__ Wn,
    const float* __restrict__ bi, const float* __restrict__ bn_b,
    const float* __restrict__ f1W,
    float* __restrict__ ws)
{
    const int b  = blockIdx.x;     // 0..63
    const int t  = threadIdx.x;    // 0..255 (= k mod 256)
    const int c0 = b * 4;

    const float ck = beta[t];
    const float4 wi0 = *reinterpret_cast<const float4*>(&Wi[(size_t)t * HID + c0]);
    const float4 wi1 = *reinterpret_cast<const float4*>(&Wi[(size_t)(t + 256) * HID + c0]);
    const float4 wn0 = *reinterpret_cast<const float4*>(&Wn[(size_t)t * HID + c0]);
    const float4 wn1 = *reinterpret_cast<const float4*>(&Wn[(size_t)(t + 256) * HID + c0]);

    float v[8];
    v[0] = ck * (wi0.x + wi1.x); v[1] = ck * (wi0.y + wi1.y);
    v[2] = ck * (wi0.z + wi1.z); v[3] = ck * (wi0.w + wi1.w);
    v[4] = ck * (wn0.x + wn1.x); v[5] = ck * (wn0.y + wn1.y);
    v[6] = ck * (wn0.z + wn1.z); v[7] = ck * (wn0.w + wn1.w);

    #pragma unroll
    for (int off = 32; off > 0; off >>= 1) {
        #pragma unroll
        for (int j = 0; j < 8; ++j) v[j] += __shfl_xor(v[j], off, 64);
    }

    __shared__ float lds[4][8];
    __shared__ float hv4[4];
    const int lane = t & 63, wid = t >> 6;
    if (lane == 0) {
        #pragma unroll
        for (int j = 0; j < 8; ++j) lds[wid][j] = v[j];
    }
    __syncthreads();
    if (t < 4) {
        const float ai = lds[0][t] + lds[1][t] + lds[2][t] + lds[3][t];
        const float an = lds[0][4 + t] + lds[1][4 + t] + lds[2][4 + t] + lds[3][4 + t];
        const int c = c0 + t;
        const float iv = 1.f / (1.f + __expf(-(ai + bi[c])));
        const float nv = tanhf(an + bn_b[c]);
        hv4[t] = (1.f - iv) * nv;          // h[c] = (1-i)*n
    }
    __syncthreads();

    // f1 partials: p1[b][t] = sum_{i<4} h[c0+i] * f1W[c0+i][t]
    const float p = hv4[0] * f1W[(size_t)(c0 + 0) * HID + t]
                  + hv4[1] * f1W[(size_t)(c0 + 1) * HID + t]
                  + hv4[2] * f1W[(size_t)(c0 + 2) * HID + t]
                  + hv4[3] * f1W[(size_t)(c0 + 3) * HID + t];
    ws[WS_P1 + b * 256 + t] = p;
}

// ---- K2: reduce p1 -> o1; f2 cols -> o2[c0..c0+4); f3 partials ---------------
__global__ __launch_bounds__(256) void f1r_f2_f3p(
    const float* __restrict__ f1b,
    const float* __restrict__ f2W, const float* __restrict__ f2b,
    const float* __restrict__ f3W,
    float* __restrict__ ws)
{
    const int b  = blockIdx.x;     // 0..63
    const int t  = threadIdx.x;    // 0..255
    const int c0 = b * 4;

    // o1[t] = relu(sum_b p1[b][t] + f1b[t])
    float a = 0.f;
    #pragma unroll 8
    for (int k = 0; k < 64; ++k) a += ws[WS_P1 + k * 256 + t];
    const float o1 = fmaxf(a + f1b[t], 0.f);

    // f2 columns c0..c0+3
    const float4 w = *reinterpret_cast<const float4*>(&f2W[(size_t)t * HID + c0]);
    float v[4] = {o1 * w.x, o1 * w.y, o1 * w.z, o1 * w.w};
    #pragma unroll
    for (int off = 32; off > 0; off >>= 1) {
        #pragma unroll
        for (int j = 0; j < 4; ++j) v[j] += __shfl_xor(v[j], off, 64);
    }

    __shared__ float lds[4][4];
    __shared__ float o2s[4];
    const int lane = t & 63, wid = t >> 6;
    if (lane == 0) {
        #pragma unroll
        for (int j = 0; j < 4; ++j) lds[wid][j] = v[j];
    }
    __syncthreads();
    if (t < 4) {
        const float s = lds[0][t] + lds[1][t] + lds[2][t] + lds[3][t];
        o2s[t] = fmaxf(s + f2b[c0 + t], 0.f);
    }
    __syncthreads();

    // f3 partials: p3[b][j] = sum_{i<4} o2[c0+i] * f3W[c0+i][j]
    if (t < NOUT) {
        const float p = o2s[0] * f3W[(size_t)(c0 + 0) * NOUT + t]
                      + o2s[1] * f3W[(size_t)(c0 + 1) * NOUT + t]
                      + o2s[2] * f3W[(size_t)(c0 + 2) * NOUT + t]
                      + o2s[3] * f3W[(size_t)(c0 + 3) * NOUT + t];
        ws[WS_P3 + b * NOUT + t] = p;
    }
}

// ---- K3: reduce p3 -> L, softmax; gumbel 2 STRIDED rows/thread (r, r+256) ----
__global__ __launch_bounds__(256) void gumbel_red(
    const float* __restrict__ gn,   // [rows, 8] fp32
    const float* __restrict__ ws,   // p3 at WS_P3
    const float* __restrict__ f3b,  // [8]
    float* __restrict__ out,        // g_graph [rows,8] then prob [rows,8]
    int rows)
{
    const int t  = threadIdx.x;
    const int rA = blockIdx.x * 512 + t;         // row 1
    const int rB = rA + 256;                     // row 2

    // issue both rows' loads first; every instruction is a contiguous
    // 64 lanes x 16B = 1KB span (per-instruction coalescing), NT read-once
    f4 ga = {0.f,0.f,0.f,0.f}, gb = ga, gc = ga, gd = ga;
    if (rA < rows) {
        const f4* gp = reinterpret_cast<const f4*>(gn + (size_t)rA * NOUT);
        ga = __builtin_nontemporal_load(gp);
        gb = __builtin_nontemporal_load(gp + 1);
    }
    if (rB < rows) {
        const f4* gp = reinterpret_cast<const f4*>(gn + (size_t)rB * NOUT);
        gc = __builtin_nontemporal_load(gp);
        gd = __builtin_nontemporal_load(gp + 1);
    }

    // preamble: reduce p3 -> L, softmax (wave 0 only; hidden under loads)
    __shared__ float sLp[16];
    if (t < 64) {
        const float4 pa = *reinterpret_cast<const float4*>(&ws[WS_P3 + t * NOUT]);
        const float4 pb = *reinterpret_cast<const float4*>(&ws[WS_P3 + t * NOUT + 4]);
        float v[NOUT] = {pa.x, pa.y, pa.z, pa.w, pb.x, pb.y, pb.z, pb.w};
        #pragma unroll
        for (int off = 32; off > 0; off >>= 1) {
            #pragma unroll
            for (int j = 0; j < NOUT; ++j) v[j] += __shfl_xor(v[j], off, 64);
        }
        if (t == 0) {
            float L[NOUT];
            #pragma unroll
            for (int j = 0; j < NOUT; ++j) L[j] = v[j] + f3b[j];
            float m = L[0];
            #pragma unroll
            for (int j = 1; j < NOUT; ++j) m = fmaxf(m, L[j]);
            float e[NOUT], s = 0.f;
            #pragma unroll
            for (int j = 0; j < NOUT; ++j) { e[j] = __expf(L[j] - m); s += e[j]; }
            const float inv = 1.f / s;
            #pragma unroll
            for (int j = 0; j < NOUT; ++j) {
                sLp[j]     = 2.f * L[j];     // pre-scaled by 1/TAU = 2
                sLp[8 + j] = e[j] * inv;     // prob
            }
        }
    }
    __syncthreads();

    float L2[NOUT];
    #pragma unroll
    for (int j = 0; j < NOUT; ++j) L2[j] = sLp[j];
    const f4 pr0 = {sLp[8],  sLp[9],  sLp[10], sLp[11]};
    const f4 pr1 = {sLp[12], sLp[13], sLp[14], sLp[15]};

    // ---- row A ----
    if (rA < rows) {
        float z[NOUT] = {ga.x, ga.y, ga.z, ga.w, gb.x, gb.y, gb.z, gb.w};
        float m = -1e30f;
        #pragma unroll
        for (int j = 0; j < NOUT; ++j) { z[j] = L2[j] + 2.f * z[j]; m = fmaxf(m, z[j]); }
        float s = 0.f;
        #pragma unroll
        for (int j = 0; j < NOUT; ++j) { z[j] = __expf(z[j] - m); s += z[j]; }
        const float inv = 1.f / s;
        f4* op = reinterpret_cast<f4*>(out + (size_t)rA * NOUT);
        f4 z0 = {z[0]*inv, z[1]*inv, z[2]*inv, z[3]*inv};
        f4 z1 = {z[4]*inv, z[5]*inv, z[6]*inv, z[7]*inv};
        __builtin_nontemporal_store(z0, op);
        __builtin_nontemporal_store(z1, op + 1);
        f4* pp = reinterpret_cast<f4*>(out + (size_t)(rows + rA) * NOUT);
        __builtin_nontemporal_store(pr0, pp);
        __builtin_nontemporal_store(pr1, pp + 1);
    }
    // ---- row B ----
    if (rB < rows) {
        float z[NOUT] = {gc.x, gc.y, gc.z, gc.w, gd.x, gd.y, gd.z, gd.w};
        float m = -1e30f;
        #pragma unroll
        for (int j = 0; j < NOUT; ++j) { z[j] = L2[j] + 2.f * z[j]; m = fmaxf(m, z[j]); }
        float s = 0.f;
        #pragma unroll
        for (int j = 0; j < NOUT; ++j) { z[j] = __expf(z[j] - m); s += z[j]; }
        const float inv = 1.f / s;
        f4* op = reinterpret_cast<f4*>(out + (size_t)rB * NOUT);
        f4 z0 = {z[0]*inv, z[1]*inv, z[2]*inv, z[3]*inv};
        f4 z1 = {z[4]*inv, z[5]*inv, z[6]*inv, z[7]*inv};
        __builtin_nontemporal_store(z0, op);
        __builtin_nontemporal_store(z1, op + 1);
        f4* pp = reinterpret_cast<f4*>(out + (size_t)(rows + rB) * NOUT);
        __builtin_nontemporal_store(pr0, pp);
        __builtin_nontemporal_store(pr1, pp + 1);
    }
}

extern "C" void kernel_launch(void* const* d_in, const int* in_sizes, int n_in,
                              void* d_out, int out_size, void* d_ws, size_t ws_size,
                              hipStream_t stream) {
    // 0 graph, 1 rel_rec, 2 rel_send, 3 gumbel_noise,
    // 4 m1_W1, 5 m1_b1, 6 m1_W2, 7 m1_b2, 8 m1_g, 9 m1_beta,
    // 10 m2_W1, 11 m2_b1, 12 m2_W2, 13 m2_b2, 14 m2_g, 15 m2_beta,
    // 16 Wi, 17 bi, 18 Wn, 19 bn_b, 20 f1_W, 21 f1_b, 22 f2_W, 23 f2_b,
    // 24 f3_W, 25 f3_b
    const float* gumbel  = (const float*)d_in[3];
    const float* m2_beta = (const float*)d_in[15];
    const float* Wi      = (const float*)d_in[16];
    const float* bi      = (const float*)d_in[17];
    const float* Wn      = (const float*)d_in[18];
    const float* bn_b    = (const float*)d_in[19];
    const float* f1W     = (const float*)d_in[20];
    const float* f1b     = (const float*)d_in[21];
    const float* f2W     = (const float*)d_in[22];
    const float* f2b     = (const float*)d_in[23];
    const float* f3W     = (const float*)d_in[24];
    const float* f3b     = (const float*)d_in[25];

    const int rows = in_sizes[3] / NOUT;   // 260096
    float* ws = (float*)d_ws;

    gate_f1p<<<64, 256, 0, stream>>>(m2_beta, Wi, Wn, bi, bn_b, f1W, ws);
    f1r_f2_f3p<<<64, 256, 0, stream>>>(f1b, f2W, f2b, f3W, ws);

    const int blocks = (rows + 511) / 512;   // 508
    gumbel_red<<<blocks, 256, 0, stream>>>(gumbel, ws, f3b, (float*)d_out, rows);
}